// Round 15
// baseline (188.055 us; speedup 1.0000x reference)
//
#include <hip/hip_runtime.h>
#include <hip/hip_bf16.h>
#include <cmath>

// GAT layer.  B=4, N=2047 (+1 prior), I=256, O=128, H=4.  bf16 in/out.
// exp(leakyrelu(si+sj)) factorizes per branch; bucket j by s_dst (256 bins),
// per-bin channel sums, prefix/suffix over bins, boundary bin element-wise.
// R15: consolidation on the best measured structure (R11, 161.2us):
// ktr fused into k0 (flags live in LDS); k3c1+k3c2 fused (R12's k3c_scan).
// 9 -> 7 dispatches; math bit-identical to R11.

#define B_ 4
#define N_ 2047
#define N1 2048
#define I_ 256
#define O_ 128
#define H_ 4
#define NBINS 256
#define NCHUNK 4
#define CBINS (NBINS / NCHUNK)
#define STR 132
#define SLOPEC 0.2f
#define HS_STR 136
#define XS_STR 72

typedef unsigned short u16;
typedef unsigned char u8;
typedef short bf16x8 __attribute__((ext_vector_type(8)));
typedef float f32x4 __attribute__((ext_vector_type(4)));
#define MFMA16(a,b,c) __builtin_amdgcn_mfma_f32_16x16x32_bf16(a,b,c,0,0,0)

__device__ __forceinline__ float bf2f(u16 v){
  union { unsigned u; float f; } x; x.u = ((unsigned)v) << 16; return x.f;
}
__device__ __forceinline__ u16 f2bf(float f){
  union { float f; unsigned u; } x; x.f = f;
  unsigned u = x.u;
  return (u16)((u + 0x7FFFu + ((u >> 16) & 1u)) >> 16);
}
__device__ __forceinline__ float ldv(const void* p, int bf, size_t i){
  if (bf) return bf2f(reinterpret_cast<const u16*>(p)[i]);
  return reinterpret_cast<const float*>(p)[i];
}
__device__ __forceinline__ void ld8(const void* p, int bf, size_t i, float* o){
  if (bf){
    uint4 v = *reinterpret_cast<const uint4*>(reinterpret_cast<const u16*>(p) + i);
    o[0]=bf2f((u16)(v.x&0xFFFF)); o[1]=bf2f((u16)(v.x>>16));
    o[2]=bf2f((u16)(v.y&0xFFFF)); o[3]=bf2f((u16)(v.y>>16));
    o[4]=bf2f((u16)(v.z&0xFFFF)); o[5]=bf2f((u16)(v.z>>16));
    o[6]=bf2f((u16)(v.w&0xFFFF)); o[7]=bf2f((u16)(v.w>>16));
  } else {
    const float4* q = reinterpret_cast<const float4*>(reinterpret_cast<const float*>(p) + i);
    float4 a = q[0], b = q[1];
    o[0]=a.x; o[1]=a.y; o[2]=a.z; o[3]=a.w;
    o[4]=b.x; o[5]=b.y; o[6]=b.z; o[7]=b.w;
  }
}
__device__ __forceinline__ void st8bf(u16* dst, const void* src, int bf, size_t i){
  if (bf){
    *reinterpret_cast<uint4*>(dst) =
      *reinterpret_cast<const uint4*>(reinterpret_cast<const u16*>(src) + i);
  } else {
    float v[8]; ld8(src, 0, i, v);
    u16 tmp[8];
#pragma unroll
    for (int m = 0; m < 8; m++) tmp[m] = f2bf(v[m]);
    *reinterpret_cast<uint4*>(dst) = *reinterpret_cast<uint4*>(tmp);
  }
}
__device__ __forceinline__ float clS(float v){ return fminf(30.f, fmaxf(-30.f, v)); }
__device__ __forceinline__ float clH(float v){ return fminf(1e4f, fmaxf(-1e4f, v)); }
__device__ __forceinline__ int binOf(float v, float lo, float inv){
  int c = (int)((v - lo) * inv);
  c = c < 0 ? 0 : c;
  c = c > NBINS - 1 ? NBINS - 1 : c;
  return c;
}
__device__ __forceinline__ int rdmask(const u8* m, int mode, int idx){
  return mode ? (m[idx] != 0) : (((const int*)m)[idx] != 0);
}

// K0: dtype flags + colsum zero + wT transpose (ktr fused — flags in LDS)
__global__ __launch_bounds__(1024) void k0_detect(const u8* __restrict__ mask,
                                                  const void* x, const void* prior,
                                                  const void* Wlin, const void* wh,
                                                  const void* asr, const void* ads,
                                                  int* __restrict__ flags,
                                                  float* __restrict__ colsum,
                                                  u16* __restrict__ wT){
  __shared__ int c[8];
  const int t = threadIdx.x;
  for (int i = t; i < B_ * H_ * O_; i += 1024) colsum[i] = 0.f;
  if (t < 8) c[t] = 0;
  __syncthreads();
  int local = 0;
  for (int i = t; i < B_ * N1; i += 1024)
    if ((i & 3) && mask[i]) local = 1;
  if (local) atomicOr(&c[0], 1);
  const void* ptrs[6] = {x, prior, Wlin, wh, asr, ads};
  const int   lens[6] = {4096, 512, 4096, 4096, 512, 512};
  for (int k = 0; k < 6; k++){
    const u16* p = (const u16*)ptrs[k];
    int g = 0;
    for (int i = t; i < lens[k]; i += 1024){
      int e = (p[i] >> 7) & 0xFF;
      if (e >= 0xC0) g++;
    }
    if (g) atomicAdd(&c[k + 1], g);
  }
  __syncthreads();
  if (t == 0) flags[0] = c[0];
  else if (t <= 6) flags[t] = (c[t] < 4) ? 1 : 0;
  // fused ktr: wT[h][p][o] = bf16(w_head[h][o][p]); fw from LDS
  const int fw = (c[4] < 4) ? 1 : 0;
  for (int idx = t; idx < H_ * O_ * O_; idx += 1024){
    const int h = idx >> 14, rem = idx & 16383, p = rem >> 7, o = rem & 127;
    wT[idx] = f2bf(ldv(wh, fw, ((size_t)h * O_ + o) * O_ + p));
  }
}

// K1 (MFMA): hpb = bf16(x @ Wlin^T); row 2047 = prior
__global__ __launch_bounds__(256) void k1_hp(const void* __restrict__ x,
                                             const void* __restrict__ prior,
                                             const void* __restrict__ Wlin,
                                             const int* __restrict__ flags,
                                             u16* __restrict__ hpb){
  __shared__ __align__(16) u16 xs[32 * XS_STR];
  __shared__ __align__(16) u16 wl[128 * XS_STR];
  const int fx = flags[1], fpf = flags[2], fw = flags[3];
  const int tile = blockIdx.x & 63;
  const int b    = blockIdx.x >> 6;
  const int n0   = tile * 32;
  const int t = threadIdx.x;
  const int w = t >> 6, lane = t & 63, m16 = lane & 15, q = lane >> 4;
  const int rbase = (w & 1) * 16;
  const int cbase = (w >> 1) * 64;
  f32x4 acc[4];
#pragma unroll
  for (int nt = 0; nt < 4; nt++) acc[nt] = (f32x4){0.f, 0.f, 0.f, 0.f};
  for (int kt = 0; kt < I_; kt += 64){
    if (kt) __syncthreads();
    {
      const int row = t >> 3, ch = t & 7;
      const int n = n0 + row;
      if (n < N_) st8bf(&xs[row * XS_STR + ch * 8], x, fx, ((size_t)b * N_ + n) * I_ + kt + ch * 8);
      else { uint4 z = make_uint4(0,0,0,0); *reinterpret_cast<uint4*>(&xs[row * XS_STR + ch * 8]) = z; }
    }
#pragma unroll
    for (int it = 0; it < 4; it++){
      const int slot = t + it * 256, row = slot >> 3, ch = slot & 7;
      st8bf(&wl[row * XS_STR + ch * 8], Wlin, fw, (size_t)row * I_ + kt + ch * 8);
    }
    __syncthreads();
#pragma unroll
    for (int ks = 0; ks < 2; ks++){
      const int k0 = ks * 32 + q * 8;
      const bf16x8 af = *reinterpret_cast<const bf16x8*>(&xs[(rbase + m16) * XS_STR + k0]);
#pragma unroll
      for (int nt = 0; nt < 4; nt++){
        const bf16x8 bfr = *reinterpret_cast<const bf16x8*>(&wl[(cbase + nt * 16 + m16) * XS_STR + k0]);
        acc[nt] = MFMA16(af, bfr, acc[nt]);
      }
    }
  }
#pragma unroll
  for (int nt = 0; nt < 4; nt++){
#pragma unroll
    for (int r = 0; r < 4; r++){
      const int n = n0 + rbase + q * 4 + r;
      const int col = cbase + nt * 16 + m16;
      const float v = (n == N_) ? ldv(prior, fpf, b * O_ + col) : acc[nt][r];
      hpb[((size_t)b * N1 + n) * O_ + col] = f2bf(v);
    }
  }
}

// K2 (MFMA): hph = hp @ w_head[h] (stored fp32); tanh -> s_src/s_dst; colsum
__global__ __launch_bounds__(256) void k2_heads(const u16* __restrict__ hpb,
                                                const u16* __restrict__ wT,
                                                const void* __restrict__ a_src,
                                                const void* __restrict__ a_dst,
                                                const int* __restrict__ flags,
                                                float* __restrict__ hph,
                                                float* __restrict__ s_src,
                                                float* __restrict__ s_dst,
                                                float* __restrict__ colsum){
  __shared__ __align__(16) u16 hsb[64 * HS_STR];
  __shared__ __align__(16) u16 wtb[128 * HS_STR];
  __shared__ float colacc[O_];
  const int fas = flags[5], fad = flags[6];
  const int tile = blockIdx.x & 31;
  const int h    = (blockIdx.x >> 5) & 3;
  const int b    = blockIdx.x >> 7;
  const int bh   = b * H_ + h;
  const int n0   = tile * 64;
  const int t = threadIdx.x;
  const int w = t >> 6, lane = t & 63, m16 = lane & 15, q = lane >> 4;
  if (t < O_) colacc[t] = 0.f;
#pragma unroll
  for (int it = 0; it < 4; it++){
    const int slot = t + it * 256, row = slot >> 4, ch = slot & 15;
    *reinterpret_cast<uint4*>(&hsb[row * HS_STR + ch * 8]) =
      *reinterpret_cast<const uint4*>(&hpb[((size_t)b * N1 + n0 + row) * O_ + ch * 8]);
  }
#pragma unroll
  for (int it = 0; it < 8; it++){
    const int slot = t + it * 256, row = slot >> 4, ch = slot & 15;
    *reinterpret_cast<uint4*>(&wtb[row * HS_STR + ch * 8]) =
      *reinterpret_cast<const uint4*>(&wT[((size_t)h * O_ + row) * O_ + ch * 8]);
  }
  __syncthreads();
  f32x4 acc[8];
#pragma unroll
  for (int nt = 0; nt < 8; nt++) acc[nt] = (f32x4){0.f, 0.f, 0.f, 0.f};
#pragma unroll
  for (int ks = 0; ks < 4; ks++){
    const int k0 = ks * 32 + q * 8;
    const bf16x8 af = *reinterpret_cast<const bf16x8*>(&hsb[(w * 16 + m16) * HS_STR + k0]);
#pragma unroll
    for (int nt = 0; nt < 8; nt++){
      const bf16x8 bfr = *reinterpret_cast<const bf16x8*>(&wtb[(nt * 16 + m16) * HS_STR + k0]);
      acc[nt] = MFMA16(af, bfr, acc[nt]);
    }
  }
  float ps[4] = {0.f, 0.f, 0.f, 0.f}, pd[4] = {0.f, 0.f, 0.f, 0.f};
#pragma unroll
  for (int nt = 0; nt < 8; nt++){
    const int col = nt * 16 + m16;
    const float asv = ldv(a_src, fas, h * O_ + col);
    const float adv = ldv(a_dst, fad, h * O_ + col);
    float colpart = 0.f;
#pragma unroll
    for (int r = 0; r < 4; r++){
      const float v = clH(acc[nt][r]);
      hph[((size_t)bh * N1 + n0 + w * 16 + q * 4 + r) * O_ + col] = v;
      colpart += v;
      const float tv = tanhf(v);
      ps[r] += tv * asv;
      pd[r] += tv * adv;
    }
    atomicAdd(&colacc[col], colpart);
  }
#pragma unroll
  for (int r = 0; r < 4; r++){
#pragma unroll
    for (int m = 8; m > 0; m >>= 1){
      ps[r] += __shfl_xor(ps[r], m);
      pd[r] += __shfl_xor(pd[r], m);
    }
    if (m16 == 0){
      const int n = n0 + w * 16 + q * 4 + r;
      s_src[(size_t)bh * N1 + n] = ps[r];
      s_dst[(size_t)bh * N1 + n] = pd[r];
    }
  }
  __syncthreads();
  if (t < O_) atomicAdd(&colsum[bh * O_ + t], colacc[t]);
}

// K3a: range (fused) + counting sort of unmasked j by bin
__global__ __launch_bounds__(256) void k3a_bucket(const float* __restrict__ s_dst,
                                                  const u8* __restrict__ mask,
                                                  const int* __restrict__ flags,
                                                  float* __restrict__ sdlo,
                                                  float* __restrict__ sdinv,
                                                  int* __restrict__ binStart,
                                                  int* __restrict__ order){
  __shared__ float smn[4], smx[4];
  __shared__ float sli[2];
  __shared__ int cnt[NBINS];
  __shared__ int part[256];
  __shared__ int offs[256 + 1];
  const int bh = blockIdx.x, b = bh / H_, t = threadIdx.x;
  const int md = flags[0];
  float mn = 3e38f, mx = -3e38f;
  for (int j = t; j < N1; j += 256){
    if (!rdmask(mask, md, b * N1 + j)){
      float v = clS(s_dst[(size_t)bh * N1 + j]);
      mn = fminf(mn, v); mx = fmaxf(mx, v);
    }
  }
#pragma unroll
  for (int sft = 32; sft > 0; sft >>= 1){
    mn = fminf(mn, __shfl_down(mn, sft));
    mx = fmaxf(mx, __shfl_down(mx, sft));
  }
  if ((t & 63) == 0){ smn[t >> 6] = mn; smx[t >> 6] = mx; }
  __syncthreads();
  if (t == 0){
    mn = fminf(fminf(smn[0], smn[1]), fminf(smn[2], smn[3]));
    mx = fmaxf(fmaxf(smx[0], smx[1]), fmaxf(smx[2], smx[3]));
    float range = mx - mn;
    if (!(range > 1e-30f)) range = 1.f;
    const float inv = (float)NBINS / range;
    sdlo[bh]  = mn;
    sdinv[bh] = inv;
    sli[0] = mn; sli[1] = inv;
  }
  __syncthreads();
  const float lo = sli[0], inv = sli[1];
  cnt[t] = 0;
  __syncthreads();
  for (int j = t; j < N1; j += 256){
    if (!rdmask(mask, md, b * N1 + j))
      atomicAdd(&cnt[binOf(clS(s_dst[(size_t)bh * N1 + j]), lo, inv)], 1);
  }
  __syncthreads();
  const int mysum = cnt[t];
  part[t] = mysum;
  __syncthreads();
  for (int off = 1; off < 256; off <<= 1){
    int v = (t >= off) ? part[t - off] : 0;
    __syncthreads();
    part[t] += v;
    __syncthreads();
  }
  const int excl = part[t] - mysum;
  offs[t] = excl;
  binStart[bh * (NBINS + 1) + t] = excl;
  if (t == 255) binStart[bh * (NBINS + 1) + NBINS] = part[255];
  __syncthreads();
  for (int j = t; j < N1; j += 256){
    if (!rdmask(mask, md, b * N1 + j)){
      int bin = binOf(clS(s_dst[(size_t)bh * N1 + j]), lo, inv);
      int pos = atomicAdd(&offs[bin], 1);
      order[(size_t)bh * N1 + pos] = j;
    }
  }
}

// K3b: per-bin sums over hph channels (channel 128 = ones)
__global__ __launch_bounds__(192) void k3b_binsum(const float* __restrict__ hph,
                                                  const float* __restrict__ s_dst,
                                                  const int* __restrict__ binStart,
                                                  const int* __restrict__ order,
                                                  float* __restrict__ binPos,
                                                  float* __restrict__ binNeg){
  __shared__ int jls[64];
  __shared__ float fpl[64], fnl[64];
  const int gb = blockIdx.x;
  const int bh = gb / NBINS, bin = gb % NBINS;
  const int t = threadIdx.x;
  const int s = binStart[bh * (NBINS + 1) + bin];
  const int e = binStart[bh * (NBINS + 1) + bin + 1];
  float ap = 0.f, an = 0.f;
  for (int mb = s; mb < e; mb += 64){
    const int cn = min(64, e - mb);
    if (t < cn){
      const int j = order[(size_t)bh * N1 + mb + t];
      const float sdj = clS(s_dst[(size_t)bh * N1 + j]);
      jls[t] = j;
      fpl[t] = __expf(sdj);
      fnl[t] = __expf(SLOPEC * sdj);
    }
    __syncthreads();
    for (int m = 0; m < cn; m++){
      const float v = (t < O_) ? hph[((size_t)bh * N1 + jls[m]) * O_ + t] : 1.f;
      ap += fpl[m] * v;
      an += fnl[m] * v;
    }
    __syncthreads();
  }
  if (t <= O_){
    const size_t basei = ((size_t)bh * NBINS + bin) * STR;
    binPos[basei + t] = ap;
    binNeg[basei + t] = an;
  }
}

// K3c: fused hierarchical prefix/suffix; 1 block per (arr,bh)
__global__ __launch_bounds__(576) void k3c_scan(const float* __restrict__ binPos,
                                                const float* __restrict__ binNeg,
                                                float* __restrict__ sufPos,
                                                float* __restrict__ preNeg){
  __shared__ float csum[NCHUNK][132];
  const int blk = blockIdx.x;            // 32 = 2 arr x 16 bh
  const int bh = blk & 15, arr = blk >> 4;
  const int t = threadIdx.x;
  const bool act = t < NCHUNK * 129;
  const int ch = act ? (t % 129) : 0;
  const int chunk = act ? (t / 129) : 0;
  const float* src = arr ? binPos : binNeg;
  if (act){
    float s = 0.f;
    const size_t base = ((size_t)bh * NBINS + chunk * CBINS) * STR + ch;
    for (int r = 0; r < CBINS; r++) s += src[base + (size_t)r * STR];
    csum[chunk][ch] = s;
  }
  __syncthreads();
  if (act){
    if (arr == 0){
      float acc = 0.f;
      for (int cc = 0; cc < chunk; cc++) acc += csum[cc][ch];
      for (int rr = 0; rr < CBINS; rr++){
        const int r = chunk * CBINS + rr;
        preNeg[((size_t)bh * (NBINS + 1) + r) * STR + ch] = acc;
        acc += binNeg[((size_t)bh * NBINS + r) * STR + ch];
      }
      if (chunk == NCHUNK - 1) preNeg[((size_t)bh * (NBINS + 1) + NBINS) * STR + ch] = acc;
    } else {
      float acc = 0.f;
      for (int cc = chunk + 1; cc < NCHUNK; cc++) acc += csum[cc][ch];
      for (int rr = CBINS - 1; rr >= 0; rr--){
        const int r = chunk * CBINS + rr;
        acc += binPos[((size_t)bh * NBINS + r) * STR + ch];
        sufPos[((size_t)bh * (NBINS + 1) + r) * STR + ch] = acc;
      }
      if (chunk == NCHUNK - 1) sufPos[((size_t)bh * (NBINS + 1) + NBINS) * STR + ch] = 0.f;
    }
  }
}

// K3d: 1 row/block, 512 thr (4 heads x 128 ch); wave-shuffle members
__global__ __launch_bounds__(512) void k3d_out(const float* __restrict__ hph,
                                               const float* __restrict__ s_src,
                                               const float* __restrict__ s_dst,
                                               const u8* __restrict__ mask,
                                               const int* __restrict__ flags,
                                               const float* __restrict__ sdlo,
                                               const float* __restrict__ sdinv,
                                               const int* __restrict__ binStart,
                                               const int* __restrict__ order,
                                               const float* __restrict__ sufPos,
                                               const float* __restrict__ preNeg,
                                               const float* __restrict__ colsum,
                                               const void* __restrict__ bias,
                                               void* __restrict__ outp){
  __shared__ float part[4 * STR];
  const int blk = blockIdx.x;
  const int b = blk >> 11, i = blk & (N1 - 1);
  const int t = threadIdx.x;
  const int h = t >> 7, o = t & 127;
  const int lane = t & 63;
  const int md = flags[0], fo = flags[1];
  const int bh = b * H_ + h;
  const int U = binStart[bh * (NBINS + 1) + NBINS];
  const bool mrow = rdmask(mask, md, b * N1 + i) != 0;
  float contrib;
  if (mrow || U == 0){
    contrib = colsum[bh * O_ + o] * (1.f / N1);
  } else {
    const float si = clS(s_src[(size_t)bh * N1 + i]);
    const float tthr = -si;
    const int c = binOf(tthr, sdlo[bh], sdinv[bh]);
    const size_t rowp = ((size_t)bh * (NBINS + 1) + c + 1) * STR;
    const size_t rown = ((size_t)bh * (NBINS + 1) + c) * STR;
    float posV = sufPos[rowp + o], posS = sufPos[rowp + O_];
    float negV = preNeg[rown + o], negS = preNeg[rown + O_];
    const int s0 = binStart[bh * (NBINS + 1) + c];
    const int e0 = binStart[bh * (NBINS + 1) + c + 1];
    for (int mb = s0; mb < e0; mb += 64){
      const int cn = min(64, e0 - mb);
      int jm = 0; float sdm = 0.f, fpm = 0.f, fnm = 0.f;
      if (lane < cn){
        jm = order[(size_t)bh * N1 + mb + lane];
        sdm = clS(s_dst[(size_t)bh * N1 + jm]);
        fpm = __expf(sdm);
        fnm = __expf(SLOPEC * sdm);
      }
      int m = 0;
      for (; m + 3 < cn; m += 4){
        const int j0 = __shfl(jm, m),     j1 = __shfl(jm, m + 1);
        const int j2 = __shfl(jm, m + 2), j3 = __shfl(jm, m + 3);
        const float hv0 = hph[((size_t)bh * N1 + j0) * O_ + o];
        const float hv1 = hph[((size_t)bh * N1 + j1) * O_ + o];
        const float hv2 = hph[((size_t)bh * N1 + j2) * O_ + o];
        const float hv3 = hph[((size_t)bh * N1 + j3) * O_ + o];
        const float sd0 = __shfl(sdm, m),     sd1 = __shfl(sdm, m + 1);
        const float sd2 = __shfl(sdm, m + 2), sd3 = __shfl(sdm, m + 3);
        const float fp0 = __shfl(fpm, m),     fp1 = __shfl(fpm, m + 1);
        const float fp2 = __shfl(fpm, m + 2), fp3 = __shfl(fpm, m + 3);
        const float fn0 = __shfl(fnm, m),     fn1 = __shfl(fnm, m + 1);
        const float fn2 = __shfl(fnm, m + 2), fn3 = __shfl(fnm, m + 3);
        if (sd0 >= tthr){ posV += fp0 * hv0; posS += fp0; } else { negV += fn0 * hv0; negS += fn0; }
        if (sd1 >= tthr){ posV += fp1 * hv1; posS += fp1; } else { negV += fn1 * hv1; negS += fn1; }
        if (sd2 >= tthr){ posV += fp2 * hv2; posS += fp2; } else { negV += fn2 * hv2; negS += fn2; }
        if (sd3 >= tthr){ posV += fp3 * hv3; posS += fp3; } else { negV += fn3 * hv3; negS += fn3; }
      }
      for (; m < cn; m++){
        const int j = __shfl(jm, m);
        const float sdj = __shfl(sdm, m);
        const float fp = __shfl(fpm, m);
        const float fn = __shfl(fnm, m);
        const float hv = hph[((size_t)bh * N1 + j) * O_ + o];
        if (sdj >= tthr){ posV += fp * hv; posS += fp; }
        else            { negV += fn * hv; negS += fn; }
      }
    }
    const float esi = __expf(si), esi2 = __expf(SLOPEC * si);
    const float den = fmaxf(esi * posS + esi2 * negS, 1e-35f);
    contrib = (esi * posV + esi2 * negV) / den;
  }
  part[h * STR + o] = contrib;
  __syncthreads();
  if (t < O_){
    const float sum = part[0 * STR + t] + part[1 * STR + t] + part[2 * STR + t] + part[3 * STR + t];
    const float v = 0.25f * sum + ldv(bias, fo, t);
    const size_t oidx = ((size_t)b * N1 + i) * O_ + t;
    if (fo) ((u16*)outp)[oidx] = f2bf(v);
    else    ((float*)outp)[oidx] = v;
  }
}

extern "C" void kernel_launch(void* const* d_in, const int* in_sizes, int n_in,
                              void* d_out, int out_size, void* d_ws, size_t ws_size,
                              hipStream_t stream){
  const void* x      = d_in[0];
  const void* prior  = d_in[1];
  const u8*   mask   = (const u8*)d_in[2];
  const void* Wlin   = d_in[3];
  const void* w_head = d_in[4];
  const void* a_src  = d_in[5];
  const void* a_dst  = d_in[6];
  const void* bias   = d_in[7];

  char* basep = (char*)d_ws;
  size_t off = 0;
  auto alloc = [&](size_t bytes) -> void* {
    off = (off + 255) & ~(size_t)255;
    void* p = basep + off;
    off += bytes;
    return p;
  };
  int*   flags    = (int*)alloc(32);
  u16*   wT       = (u16*)alloc((size_t)H_ * O_ * O_ * 2);
  u16*   hpb      = (u16*)alloc((size_t)B_ * N1 * O_ * 2);
  float* hph      = (float*)alloc((size_t)B_ * H_ * N1 * O_ * 4);
  float* s_src    = (float*)alloc((size_t)B_ * H_ * N1 * 4);
  float* s_dst    = (float*)alloc((size_t)B_ * H_ * N1 * 4);
  float* sdlo     = (float*)alloc(B_ * H_ * 4);
  float* sdinv    = (float*)alloc(B_ * H_ * 4);
  float* colsum   = (float*)alloc((size_t)B_ * H_ * O_ * 4);
  int*   binStart = (int*)alloc((size_t)B_ * H_ * (NBINS + 1) * 4);
  int*   order    = (int*)alloc((size_t)B_ * H_ * N1 * 4);
  float* binPos   = (float*)alloc((size_t)B_ * H_ * NBINS * STR * 4);
  float* binNeg   = (float*)alloc((size_t)B_ * H_ * NBINS * STR * 4);
  float* sufPos   = (float*)alloc((size_t)B_ * H_ * (NBINS + 1) * STR * 4);
  float* preNeg   = (float*)alloc((size_t)B_ * H_ * (NBINS + 1) * STR * 4);
  (void)in_sizes; (void)n_in; (void)out_size; (void)ws_size;

  hipLaunchKernelGGL(k0_detect,  dim3(1),               dim3(1024), 0, stream, mask, x, prior, Wlin, w_head, a_src, a_dst, flags, colsum, wT);
  hipLaunchKernelGGL(k1_hp,      dim3(B_ * 64),         dim3(256), 0, stream, x, prior, Wlin, flags, hpb);
  hipLaunchKernelGGL(k2_heads,   dim3(B_ * H_ * 32),    dim3(256), 0, stream, hpb, wT, a_src, a_dst, flags, hph, s_src, s_dst, colsum);
  hipLaunchKernelGGL(k3a_bucket, dim3(B_ * H_),         dim3(256), 0, stream, s_dst, mask, flags, sdlo, sdinv, binStart, order);
  hipLaunchKernelGGL(k3b_binsum, dim3(B_ * H_ * NBINS), dim3(192), 0, stream, hph, s_dst, binStart, order, binPos, binNeg);
  hipLaunchKernelGGL(k3c_scan,   dim3(32),              dim3(576), 0, stream, binPos, binNeg, sufPos, preNeg);
  hipLaunchKernelGGL(k3d_out,    dim3(B_ * N1),         dim3(512), 0, stream, hph, s_src, s_dst, mask, flags, sdlo, sdinv, binStart, order, sufPos, preNeg, colsum, bias, d_out);
}

// Round 16
// 160.106 us; speedup vs baseline: 1.1746x; 1.1746x over previous
//
#include <hip/hip_runtime.h>
#include <hip/hip_bf16.h>
#include <cmath>

// GAT layer.  B=4, N=2047 (+1 prior), I=256, O=128, H=4.  bf16 in/out.
// exp(leakyrelu(si+sj)) factorizes per branch; bucket j by s_dst (256 bins),
// per-bin channel sums, prefix/suffix over bins, boundary bin element-wise.
// R16: revert R15's ktr-into-k0 fusion (one-block transpose serialized
// 65k strided gathers on a single CU: k0 3->47us).  ktr back to its own
// 256-block kernel (R11 form); keep the fused k3c_scan (harmless in R15).

#define B_ 4
#define N_ 2047
#define N1 2048
#define I_ 256
#define O_ 128
#define H_ 4
#define NBINS 256
#define NCHUNK 4
#define CBINS (NBINS / NCHUNK)
#define STR 132
#define SLOPEC 0.2f
#define HS_STR 136
#define XS_STR 72

typedef unsigned short u16;
typedef unsigned char u8;
typedef short bf16x8 __attribute__((ext_vector_type(8)));
typedef float f32x4 __attribute__((ext_vector_type(4)));
#define MFMA16(a,b,c) __builtin_amdgcn_mfma_f32_16x16x32_bf16(a,b,c,0,0,0)

__device__ __forceinline__ float bf2f(u16 v){
  union { unsigned u; float f; } x; x.u = ((unsigned)v) << 16; return x.f;
}
__device__ __forceinline__ u16 f2bf(float f){
  union { float f; unsigned u; } x; x.f = f;
  unsigned u = x.u;
  return (u16)((u + 0x7FFFu + ((u >> 16) & 1u)) >> 16);
}
__device__ __forceinline__ float ldv(const void* p, int bf, size_t i){
  if (bf) return bf2f(reinterpret_cast<const u16*>(p)[i]);
  return reinterpret_cast<const float*>(p)[i];
}
__device__ __forceinline__ void ld8(const void* p, int bf, size_t i, float* o){
  if (bf){
    uint4 v = *reinterpret_cast<const uint4*>(reinterpret_cast<const u16*>(p) + i);
    o[0]=bf2f((u16)(v.x&0xFFFF)); o[1]=bf2f((u16)(v.x>>16));
    o[2]=bf2f((u16)(v.y&0xFFFF)); o[3]=bf2f((u16)(v.y>>16));
    o[4]=bf2f((u16)(v.z&0xFFFF)); o[5]=bf2f((u16)(v.z>>16));
    o[6]=bf2f((u16)(v.w&0xFFFF)); o[7]=bf2f((u16)(v.w>>16));
  } else {
    const float4* q = reinterpret_cast<const float4*>(reinterpret_cast<const float*>(p) + i);
    float4 a = q[0], b = q[1];
    o[0]=a.x; o[1]=a.y; o[2]=a.z; o[3]=a.w;
    o[4]=b.x; o[5]=b.y; o[6]=b.z; o[7]=b.w;
  }
}
__device__ __forceinline__ void st8bf(u16* dst, const void* src, int bf, size_t i){
  if (bf){
    *reinterpret_cast<uint4*>(dst) =
      *reinterpret_cast<const uint4*>(reinterpret_cast<const u16*>(src) + i);
  } else {
    float v[8]; ld8(src, 0, i, v);
    u16 tmp[8];
#pragma unroll
    for (int m = 0; m < 8; m++) tmp[m] = f2bf(v[m]);
    *reinterpret_cast<uint4*>(dst) = *reinterpret_cast<uint4*>(tmp);
  }
}
__device__ __forceinline__ float clS(float v){ return fminf(30.f, fmaxf(-30.f, v)); }
__device__ __forceinline__ float clH(float v){ return fminf(1e4f, fmaxf(-1e4f, v)); }
__device__ __forceinline__ int binOf(float v, float lo, float inv){
  int c = (int)((v - lo) * inv);
  c = c < 0 ? 0 : c;
  c = c > NBINS - 1 ? NBINS - 1 : c;
  return c;
}
__device__ __forceinline__ int rdmask(const u8* m, int mode, int idx){
  return mode ? (m[idx] != 0) : (((const int*)m)[idx] != 0);
}

// K0: dtype flags + colsum zero (R11 form)
__global__ __launch_bounds__(1024) void k0_detect(const u8* __restrict__ mask,
                                                  const void* x, const void* prior,
                                                  const void* Wlin, const void* wh,
                                                  const void* asr, const void* ads,
                                                  int* __restrict__ flags,
                                                  float* __restrict__ colsum){
  __shared__ int c[8];
  const int t = threadIdx.x;
  for (int i = t; i < B_ * H_ * O_; i += 1024) colsum[i] = 0.f;
  if (t < 8) c[t] = 0;
  __syncthreads();
  int local = 0;
  for (int i = t; i < B_ * N1; i += 1024)
    if ((i & 3) && mask[i]) local = 1;
  if (local) atomicOr(&c[0], 1);
  const void* ptrs[6] = {x, prior, Wlin, wh, asr, ads};
  const int   lens[6] = {4096, 512, 4096, 4096, 512, 512};
  for (int k = 0; k < 6; k++){
    const u16* p = (const u16*)ptrs[k];
    int g = 0;
    for (int i = t; i < lens[k]; i += 1024){
      int e = (p[i] >> 7) & 0xFF;
      if (e >= 0xC0) g++;
    }
    if (g) atomicAdd(&c[k + 1], g);
  }
  __syncthreads();
  if (t == 0) flags[0] = c[0];
  else if (t <= 6) flags[t] = (c[t] < 4) ? 1 : 0;
}

// ktr: wT[h][p][o] = bf16(w_head[h][o][p])   (256 blocks — latency spread)
__global__ __launch_bounds__(256) void ktr(const void* __restrict__ w_head,
                                           const int* __restrict__ flags,
                                           u16* __restrict__ wT){
  const int fw = flags[4];
  const int idx = blockIdx.x * 256 + threadIdx.x;
  const int h = idx >> 14, rem = idx & 16383, p = rem >> 7, o = rem & 127;
  wT[idx] = f2bf(ldv(w_head, fw, ((size_t)h * O_ + o) * O_ + p));
}

// K1 (MFMA): hpb = bf16(x @ Wlin^T); row 2047 = prior
__global__ __launch_bounds__(256) void k1_hp(const void* __restrict__ x,
                                             const void* __restrict__ prior,
                                             const void* __restrict__ Wlin,
                                             const int* __restrict__ flags,
                                             u16* __restrict__ hpb){
  __shared__ __align__(16) u16 xs[32 * XS_STR];
  __shared__ __align__(16) u16 wl[128 * XS_STR];
  const int fx = flags[1], fpf = flags[2], fw = flags[3];
  const int tile = blockIdx.x & 63;
  const int b    = blockIdx.x >> 6;
  const int n0   = tile * 32;
  const int t = threadIdx.x;
  const int w = t >> 6, lane = t & 63, m16 = lane & 15, q = lane >> 4;
  const int rbase = (w & 1) * 16;
  const int cbase = (w >> 1) * 64;
  f32x4 acc[4];
#pragma unroll
  for (int nt = 0; nt < 4; nt++) acc[nt] = (f32x4){0.f, 0.f, 0.f, 0.f};
  for (int kt = 0; kt < I_; kt += 64){
    if (kt) __syncthreads();
    {
      const int row = t >> 3, ch = t & 7;
      const int n = n0 + row;
      if (n < N_) st8bf(&xs[row * XS_STR + ch * 8], x, fx, ((size_t)b * N_ + n) * I_ + kt + ch * 8);
      else { uint4 z = make_uint4(0,0,0,0); *reinterpret_cast<uint4*>(&xs[row * XS_STR + ch * 8]) = z; }
    }
#pragma unroll
    for (int it = 0; it < 4; it++){
      const int slot = t + it * 256, row = slot >> 3, ch = slot & 7;
      st8bf(&wl[row * XS_STR + ch * 8], Wlin, fw, (size_t)row * I_ + kt + ch * 8);
    }
    __syncthreads();
#pragma unroll
    for (int ks = 0; ks < 2; ks++){
      const int k0 = ks * 32 + q * 8;
      const bf16x8 af = *reinterpret_cast<const bf16x8*>(&xs[(rbase + m16) * XS_STR + k0]);
#pragma unroll
      for (int nt = 0; nt < 4; nt++){
        const bf16x8 bfr = *reinterpret_cast<const bf16x8*>(&wl[(cbase + nt * 16 + m16) * XS_STR + k0]);
        acc[nt] = MFMA16(af, bfr, acc[nt]);
      }
    }
  }
#pragma unroll
  for (int nt = 0; nt < 4; nt++){
#pragma unroll
    for (int r = 0; r < 4; r++){
      const int n = n0 + rbase + q * 4 + r;
      const int col = cbase + nt * 16 + m16;
      const float v = (n == N_) ? ldv(prior, fpf, b * O_ + col) : acc[nt][r];
      hpb[((size_t)b * N1 + n) * O_ + col] = f2bf(v);
    }
  }
}

// K2 (MFMA): hph = hp @ w_head[h] (stored fp32); tanh -> s_src/s_dst; colsum
__global__ __launch_bounds__(256) void k2_heads(const u16* __restrict__ hpb,
                                                const u16* __restrict__ wT,
                                                const void* __restrict__ a_src,
                                                const void* __restrict__ a_dst,
                                                const int* __restrict__ flags,
                                                float* __restrict__ hph,
                                                float* __restrict__ s_src,
                                                float* __restrict__ s_dst,
                                                float* __restrict__ colsum){
  __shared__ __align__(16) u16 hsb[64 * HS_STR];
  __shared__ __align__(16) u16 wtb[128 * HS_STR];
  __shared__ float colacc[O_];
  const int fas = flags[5], fad = flags[6];
  const int tile = blockIdx.x & 31;
  const int h    = (blockIdx.x >> 5) & 3;
  const int b    = blockIdx.x >> 7;
  const int bh   = b * H_ + h;
  const int n0   = tile * 64;
  const int t = threadIdx.x;
  const int w = t >> 6, lane = t & 63, m16 = lane & 15, q = lane >> 4;
  if (t < O_) colacc[t] = 0.f;
#pragma unroll
  for (int it = 0; it < 4; it++){
    const int slot = t + it * 256, row = slot >> 4, ch = slot & 15;
    *reinterpret_cast<uint4*>(&hsb[row * HS_STR + ch * 8]) =
      *reinterpret_cast<const uint4*>(&hpb[((size_t)b * N1 + n0 + row) * O_ + ch * 8]);
  }
#pragma unroll
  for (int it = 0; it < 8; it++){
    const int slot = t + it * 256, row = slot >> 4, ch = slot & 15;
    *reinterpret_cast<uint4*>(&wtb[row * HS_STR + ch * 8]) =
      *reinterpret_cast<const uint4*>(&wT[((size_t)h * O_ + row) * O_ + ch * 8]);
  }
  __syncthreads();
  f32x4 acc[8];
#pragma unroll
  for (int nt = 0; nt < 8; nt++) acc[nt] = (f32x4){0.f, 0.f, 0.f, 0.f};
#pragma unroll
  for (int ks = 0; ks < 4; ks++){
    const int k0 = ks * 32 + q * 8;
    const bf16x8 af = *reinterpret_cast<const bf16x8*>(&hsb[(w * 16 + m16) * HS_STR + k0]);
#pragma unroll
    for (int nt = 0; nt < 8; nt++){
      const bf16x8 bfr = *reinterpret_cast<const bf16x8*>(&wtb[(nt * 16 + m16) * HS_STR + k0]);
      acc[nt] = MFMA16(af, bfr, acc[nt]);
    }
  }
  float ps[4] = {0.f, 0.f, 0.f, 0.f}, pd[4] = {0.f, 0.f, 0.f, 0.f};
#pragma unroll
  for (int nt = 0; nt < 8; nt++){
    const int col = nt * 16 + m16;
    const float asv = ldv(a_src, fas, h * O_ + col);
    const float adv = ldv(a_dst, fad, h * O_ + col);
    float colpart = 0.f;
#pragma unroll
    for (int r = 0; r < 4; r++){
      const float v = clH(acc[nt][r]);
      hph[((size_t)bh * N1 + n0 + w * 16 + q * 4 + r) * O_ + col] = v;
      colpart += v;
      const float tv = tanhf(v);
      ps[r] += tv * asv;
      pd[r] += tv * adv;
    }
    atomicAdd(&colacc[col], colpart);
  }
#pragma unroll
  for (int r = 0; r < 4; r++){
#pragma unroll
    for (int m = 8; m > 0; m >>= 1){
      ps[r] += __shfl_xor(ps[r], m);
      pd[r] += __shfl_xor(pd[r], m);
    }
    if (m16 == 0){
      const int n = n0 + w * 16 + q * 4 + r;
      s_src[(size_t)bh * N1 + n] = ps[r];
      s_dst[(size_t)bh * N1 + n] = pd[r];
    }
  }
  __syncthreads();
  if (t < O_) atomicAdd(&colsum[bh * O_ + t], colacc[t]);
}

// K3a: range (fused) + counting sort of unmasked j by bin
__global__ __launch_bounds__(256) void k3a_bucket(const float* __restrict__ s_dst,
                                                  const u8* __restrict__ mask,
                                                  const int* __restrict__ flags,
                                                  float* __restrict__ sdlo,
                                                  float* __restrict__ sdinv,
                                                  int* __restrict__ binStart,
                                                  int* __restrict__ order){
  __shared__ float smn[4], smx[4];
  __shared__ float sli[2];
  __shared__ int cnt[NBINS];
  __shared__ int part[256];
  __shared__ int offs[256 + 1];
  const int bh = blockIdx.x, b = bh / H_, t = threadIdx.x;
  const int md = flags[0];
  float mn = 3e38f, mx = -3e38f;
  for (int j = t; j < N1; j += 256){
    if (!rdmask(mask, md, b * N1 + j)){
      float v = clS(s_dst[(size_t)bh * N1 + j]);
      mn = fminf(mn, v); mx = fmaxf(mx, v);
    }
  }
#pragma unroll
  for (int sft = 32; sft > 0; sft >>= 1){
    mn = fminf(mn, __shfl_down(mn, sft));
    mx = fmaxf(mx, __shfl_down(mx, sft));
  }
  if ((t & 63) == 0){ smn[t >> 6] = mn; smx[t >> 6] = mx; }
  __syncthreads();
  if (t == 0){
    mn = fminf(fminf(smn[0], smn[1]), fminf(smn[2], smn[3]));
    mx = fmaxf(fmaxf(smx[0], smx[1]), fmaxf(smx[2], smx[3]));
    float range = mx - mn;
    if (!(range > 1e-30f)) range = 1.f;
    const float inv = (float)NBINS / range;
    sdlo[bh]  = mn;
    sdinv[bh] = inv;
    sli[0] = mn; sli[1] = inv;
  }
  __syncthreads();
  const float lo = sli[0], inv = sli[1];
  cnt[t] = 0;
  __syncthreads();
  for (int j = t; j < N1; j += 256){
    if (!rdmask(mask, md, b * N1 + j))
      atomicAdd(&cnt[binOf(clS(s_dst[(size_t)bh * N1 + j]), lo, inv)], 1);
  }
  __syncthreads();
  const int mysum = cnt[t];
  part[t] = mysum;
  __syncthreads();
  for (int off = 1; off < 256; off <<= 1){
    int v = (t >= off) ? part[t - off] : 0;
    __syncthreads();
    part[t] += v;
    __syncthreads();
  }
  const int excl = part[t] - mysum;
  offs[t] = excl;
  binStart[bh * (NBINS + 1) + t] = excl;
  if (t == 255) binStart[bh * (NBINS + 1) + NBINS] = part[255];
  __syncthreads();
  for (int j = t; j < N1; j += 256){
    if (!rdmask(mask, md, b * N1 + j)){
      int bin = binOf(clS(s_dst[(size_t)bh * N1 + j]), lo, inv);
      int pos = atomicAdd(&offs[bin], 1);
      order[(size_t)bh * N1 + pos] = j;
    }
  }
}

// K3b: per-bin sums over hph channels (channel 128 = ones)
__global__ __launch_bounds__(192) void k3b_binsum(const float* __restrict__ hph,
                                                  const float* __restrict__ s_dst,
                                                  const int* __restrict__ binStart,
                                                  const int* __restrict__ order,
                                                  float* __restrict__ binPos,
                                                  float* __restrict__ binNeg){
  __shared__ int jls[64];
  __shared__ float fpl[64], fnl[64];
  const int gb = blockIdx.x;
  const int bh = gb / NBINS, bin = gb % NBINS;
  const int t = threadIdx.x;
  const int s = binStart[bh * (NBINS + 1) + bin];
  const int e = binStart[bh * (NBINS + 1) + bin + 1];
  float ap = 0.f, an = 0.f;
  for (int mb = s; mb < e; mb += 64){
    const int cn = min(64, e - mb);
    if (t < cn){
      const int j = order[(size_t)bh * N1 + mb + t];
      const float sdj = clS(s_dst[(size_t)bh * N1 + j]);
      jls[t] = j;
      fpl[t] = __expf(sdj);
      fnl[t] = __expf(SLOPEC * sdj);
    }
    __syncthreads();
    for (int m = 0; m < cn; m++){
      const float v = (t < O_) ? hph[((size_t)bh * N1 + jls[m]) * O_ + t] : 1.f;
      ap += fpl[m] * v;
      an += fnl[m] * v;
    }
    __syncthreads();
  }
  if (t <= O_){
    const size_t basei = ((size_t)bh * NBINS + bin) * STR;
    binPos[basei + t] = ap;
    binNeg[basei + t] = an;
  }
}

// K3c: fused hierarchical prefix/suffix; 1 block per (arr,bh)
__global__ __launch_bounds__(576) void k3c_scan(const float* __restrict__ binPos,
                                                const float* __restrict__ binNeg,
                                                float* __restrict__ sufPos,
                                                float* __restrict__ preNeg){
  __shared__ float csum[NCHUNK][132];
  const int blk = blockIdx.x;            // 32 = 2 arr x 16 bh
  const int bh = blk & 15, arr = blk >> 4;
  const int t = threadIdx.x;
  const bool act = t < NCHUNK * 129;
  const int ch = act ? (t % 129) : 0;
  const int chunk = act ? (t / 129) : 0;
  const float* src = arr ? binPos : binNeg;
  if (act){
    float s = 0.f;
    const size_t base = ((size_t)bh * NBINS + chunk * CBINS) * STR + ch;
    for (int r = 0; r < CBINS; r++) s += src[base + (size_t)r * STR];
    csum[chunk][ch] = s;
  }
  __syncthreads();
  if (act){
    if (arr == 0){
      float acc = 0.f;
      for (int cc = 0; cc < chunk; cc++) acc += csum[cc][ch];
      for (int rr = 0; rr < CBINS; rr++){
        const int r = chunk * CBINS + rr;
        preNeg[((size_t)bh * (NBINS + 1) + r) * STR + ch] = acc;
        acc += binNeg[((size_t)bh * NBINS + r) * STR + ch];
      }
      if (chunk == NCHUNK - 1) preNeg[((size_t)bh * (NBINS + 1) + NBINS) * STR + ch] = acc;
    } else {
      float acc = 0.f;
      for (int cc = chunk + 1; cc < NCHUNK; cc++) acc += csum[cc][ch];
      for (int rr = CBINS - 1; rr >= 0; rr--){
        const int r = chunk * CBINS + rr;
        acc += binPos[((size_t)bh * NBINS + r) * STR + ch];
        sufPos[((size_t)bh * (NBINS + 1) + r) * STR + ch] = acc;
      }
      if (chunk == NCHUNK - 1) sufPos[((size_t)bh * (NBINS + 1) + NBINS) * STR + ch] = 0.f;
    }
  }
}

// K3d: 1 row/block, 512 thr (4 heads x 128 ch); wave-shuffle members
__global__ __launch_bounds__(512) void k3d_out(const float* __restrict__ hph,
                                               const float* __restrict__ s_src,
                                               const float* __restrict__ s_dst,
                                               const u8* __restrict__ mask,
                                               const int* __restrict__ flags,
                                               const float* __restrict__ sdlo,
                                               const float* __restrict__ sdinv,
                                               const int* __restrict__ binStart,
                                               const int* __restrict__ order,
                                               const float* __restrict__ sufPos,
                                               const float* __restrict__ preNeg,
                                               const float* __restrict__ colsum,
                                               const void* __restrict__ bias,
                                               void* __restrict__ outp){
  __shared__ float part[4 * STR];
  const int blk = blockIdx.x;
  const int b = blk >> 11, i = blk & (N1 - 1);
  const int t = threadIdx.x;
  const int h = t >> 7, o = t & 127;
  const int lane = t & 63;
  const int md = flags[0], fo = flags[1];
  const int bh = b * H_ + h;
  const int U = binStart[bh * (NBINS + 1) + NBINS];
  const bool mrow = rdmask(mask, md, b * N1 + i) != 0;
  float contrib;
  if (mrow || U == 0){
    contrib = colsum[bh * O_ + o] * (1.f / N1);
  } else {
    const float si = clS(s_src[(size_t)bh * N1 + i]);
    const float tthr = -si;
    const int c = binOf(tthr, sdlo[bh], sdinv[bh]);
    const size_t rowp = ((size_t)bh * (NBINS + 1) + c + 1) * STR;
    const size_t rown = ((size_t)bh * (NBINS + 1) + c) * STR;
    float posV = sufPos[rowp + o], posS = sufPos[rowp + O_];
    float negV = preNeg[rown + o], negS = preNeg[rown + O_];
    const int s0 = binStart[bh * (NBINS + 1) + c];
    const int e0 = binStart[bh * (NBINS + 1) + c + 1];
    for (int mb = s0; mb < e0; mb += 64){
      const int cn = min(64, e0 - mb);
      int jm = 0; float sdm = 0.f, fpm = 0.f, fnm = 0.f;
      if (lane < cn){
        jm = order[(size_t)bh * N1 + mb + lane];
        sdm = clS(s_dst[(size_t)bh * N1 + jm]);
        fpm = __expf(sdm);
        fnm = __expf(SLOPEC * sdm);
      }
      int m = 0;
      for (; m + 3 < cn; m += 4){
        const int j0 = __shfl(jm, m),     j1 = __shfl(jm, m + 1);
        const int j2 = __shfl(jm, m + 2), j3 = __shfl(jm, m + 3);
        const float hv0 = hph[((size_t)bh * N1 + j0) * O_ + o];
        const float hv1 = hph[((size_t)bh * N1 + j1) * O_ + o];
        const float hv2 = hph[((size_t)bh * N1 + j2) * O_ + o];
        const float hv3 = hph[((size_t)bh * N1 + j3) * O_ + o];
        const float sd0 = __shfl(sdm, m),     sd1 = __shfl(sdm, m + 1);
        const float sd2 = __shfl(sdm, m + 2), sd3 = __shfl(sdm, m + 3);
        const float fp0 = __shfl(fpm, m),     fp1 = __shfl(fpm, m + 1);
        const float fp2 = __shfl(fpm, m + 2), fp3 = __shfl(fpm, m + 3);
        const float fn0 = __shfl(fnm, m),     fn1 = __shfl(fnm, m + 1);
        const float fn2 = __shfl(fnm, m + 2), fn3 = __shfl(fnm, m + 3);
        if (sd0 >= tthr){ posV += fp0 * hv0; posS += fp0; } else { negV += fn0 * hv0; negS += fn0; }
        if (sd1 >= tthr){ posV += fp1 * hv1; posS += fp1; } else { negV += fn1 * hv1; negS += fn1; }
        if (sd2 >= tthr){ posV += fp2 * hv2; posS += fp2; } else { negV += fn2 * hv2; negS += fn2; }
        if (sd3 >= tthr){ posV += fp3 * hv3; posS += fp3; } else { negV += fn3 * hv3; negS += fn3; }
      }
      for (; m < cn; m++){
        const int j = __shfl(jm, m);
        const float sdj = __shfl(sdm, m);
        const float fp = __shfl(fpm, m);
        const float fn = __shfl(fnm, m);
        const float hv = hph[((size_t)bh * N1 + j) * O_ + o];
        if (sdj >= tthr){ posV += fp * hv; posS += fp; }
        else            { negV += fn * hv; negS += fn; }
      }
    }
    const float esi = __expf(si), esi2 = __expf(SLOPEC * si);
    const float den = fmaxf(esi * posS + esi2 * negS, 1e-35f);
    contrib = (esi * posV + esi2 * negV) / den;
  }
  part[h * STR + o] = contrib;
  __syncthreads();
  if (t < O_){
    const float sum = part[0 * STR + t] + part[1 * STR + t] + part[2 * STR + t] + part[3 * STR + t];
    const float v = 0.25f * sum + ldv(bias, fo, t);
    const size_t oidx = ((size_t)b * N1 + i) * O_ + t;
    if (fo) ((u16*)outp)[oidx] = f2bf(v);
    else    ((float*)outp)[oidx] = v;
  }
}

extern "C" void kernel_launch(void* const* d_in, const int* in_sizes, int n_in,
                              void* d_out, int out_size, void* d_ws, size_t ws_size,
                              hipStream_t stream){
  const void* x      = d_in[0];
  const void* prior  = d_in[1];
  const u8*   mask   = (const u8*)d_in[2];
  const void* Wlin   = d_in[3];
  const void* w_head = d_in[4];
  const void* a_src  = d_in[5];
  const void* a_dst  = d_in[6];
  const void* bias   = d_in[7];

  char* basep = (char*)d_ws;
  size_t off = 0;
  auto alloc = [&](size_t bytes) -> void* {
    off = (off + 255) & ~(size_t)255;
    void* p = basep + off;
    off += bytes;
    return p;
  };
  int*   flags    = (int*)alloc(32);
  u16*   wT       = (u16*)alloc((size_t)H_ * O_ * O_ * 2);
  u16*   hpb      = (u16*)alloc((size_t)B_ * N1 * O_ * 2);
  float* hph      = (float*)alloc((size_t)B_ * H_ * N1 * O_ * 4);
  float* s_src    = (float*)alloc((size_t)B_ * H_ * N1 * 4);
  float* s_dst    = (float*)alloc((size_t)B_ * H_ * N1 * 4);
  float* sdlo     = (float*)alloc(B_ * H_ * 4);
  float* sdinv    = (float*)alloc(B_ * H_ * 4);
  float* colsum   = (float*)alloc((size_t)B_ * H_ * O_ * 4);
  int*   binStart = (int*)alloc((size_t)B_ * H_ * (NBINS + 1) * 4);
  int*   order    = (int*)alloc((size_t)B_ * H_ * N1 * 4);
  float* binPos   = (float*)alloc((size_t)B_ * H_ * NBINS * STR * 4);
  float* binNeg   = (float*)alloc((size_t)B_ * H_ * NBINS * STR * 4);
  float* sufPos   = (float*)alloc((size_t)B_ * H_ * (NBINS + 1) * STR * 4);
  float* preNeg   = (float*)alloc((size_t)B_ * H_ * (NBINS + 1) * STR * 4);
  (void)in_sizes; (void)n_in; (void)out_size; (void)ws_size;

  hipLaunchKernelGGL(k0_detect,  dim3(1),               dim3(1024), 0, stream, mask, x, prior, Wlin, w_head, a_src, a_dst, flags, colsum);
  hipLaunchKernelGGL(ktr,        dim3(256),             dim3(256), 0, stream, w_head, flags, wT);
  hipLaunchKernelGGL(k1_hp,      dim3(B_ * 64),         dim3(256), 0, stream, x, prior, Wlin, flags, hpb);
  hipLaunchKernelGGL(k2_heads,   dim3(B_ * H_ * 32),    dim3(256), 0, stream, hpb, wT, a_src, a_dst, flags, hph, s_src, s_dst, colsum);
  hipLaunchKernelGGL(k3a_bucket, dim3(B_ * H_),         dim3(256), 0, stream, s_dst, mask, flags, sdlo, sdinv, binStart, order);
  hipLaunchKernelGGL(k3b_binsum, dim3(B_ * H_ * NBINS), dim3(192), 0, stream, hph, s_dst, binStart, order, binPos, binNeg);
  hipLaunchKernelGGL(k3c_scan,   dim3(32),              dim3(576), 0, stream, binPos, binNeg, sufPos, preNeg);
  hipLaunchKernelGGL(k3d_out,    dim3(B_ * N1),         dim3(512), 0, stream, hph, s_src, s_dst, mask, flags, sdlo, sdinv, binStart, order, sufPos, preNeg, colsum, bias, d_out);
}